// Round 5
// baseline (536.200 us; speedup 1.0000x reference)
//
#include <hip/hip_runtime.h>

// Problem constants
#define NB    2048     // users / segments
#define NP    16384    // posts
#define LL    50       // tokens per post
#define DD    300      // embedding dim
#define DP    320      // d padded to multiple of 32 (MFMA K tiles)
#define TP    52       // t rows incl. zero pad (48 outputs + 4 shift overhang)
#define NTOT  300      // total filters (100 per conv)
#define NPADF 320      // filters padded to 20 N-tiles of 16
#define INFEAT 768
#define HID2  128
#define UPB   4        // users per conv block
#define FCM   16       // users per fc block

typedef short v8s __attribute__((ext_vector_type(8)));
typedef float v4f __attribute__((ext_vector_type(4)));

__device__ __forceinline__ unsigned short f2bf(float f) {
    union { float f; unsigned u; } v; v.f = f;
    return (unsigned short)((v.u + 0x7FFF + ((v.u >> 16) & 1)) >> 16);  // RNE
}
__device__ __forceinline__ float bf2f(unsigned short u) {
    union { unsigned u; float f; } v; v.u = ((unsigned)u) << 16; return v.f;
}
__device__ __forceinline__ int lower_bound_i(const int* __restrict__ a, int n, int v) {
    int lo = 0, hi = n;
    while (lo < hi) { int mid = (lo + hi) >> 1; if (a[mid] < v) lo = mid + 1; else hi = mid; }
    return lo;
}

// ---- generic fp32 -> bf16 (used for emb table and fc_w1) ----
__global__ void emb_cvt(const float* __restrict__ in, unsigned short* __restrict__ out, int n4) {
    int i = blockIdx.x * blockDim.x + threadIdx.x;
    if (i >= n4) return;
    float4 v = ((const float4*)in)[i];
    ushort4 o; o.x = f2bf(v.x); o.y = f2bf(v.y); o.z = f2bf(v.z); o.w = f2bf(v.w);
    ((ushort4*)out)[i] = o;
}

// ---- conv weights -> bf16 fragment-order W5f[kt][s][nt][lane][8] + bias_all ----
// One MFMA B-fragment = 512 contiguous ushorts (64 lanes x 8): wave reads 1 KB coalesced.
__global__ void prep_w(const float* __restrict__ w3, const float* __restrict__ w4,
                       const float* __restrict__ w5,
                       const float* __restrict__ b3, const float* __restrict__ b4,
                       const float* __restrict__ b5,
                       unsigned short* __restrict__ W5f, float* __restrict__ bias_all) {
    int idx = blockIdx.x * blockDim.x + threadIdx.x;
    if (idx < NPADF) {
        float bv = 0.f;
        if (idx < 100) bv = b3[idx];
        else if (idx < 200) bv = b4[idx - 100];
        else if (idx < 300) bv = b5[idx - 200];
        bias_all[idx] = bv;
    }
    if (idx >= 10 * 5 * 20 * 512) return;
    int j    = idx & 7;
    int lane = (idx >> 3) & 63;
    int rest = idx >> 9;            // kt*100 + s*20 + nt
    int nt = rest % 20;
    int s  = (rest / 20) % 5;
    int kt = rest / 100;
    int col = lane & 15, quad = lane >> 4;
    int nf = nt * 16 + col;
    int d  = kt * 32 + quad * 8 + j;
    float v = 0.f;
    if (nf < NTOT && d < DD) {
        int cls = nf / 100, f = nf % 100, K = cls + 3;
        if (s < K) {
            const float* w = (cls == 0) ? w3 : (cls == 1) ? w4 : w5;
            v = w[(f * DD + d) * K + s];
        }
    }
    W5f[idx] = f2bf(v);
}

// ---- ragged segment-mean -> bf16 hist[b][52][320], vectorized ushort4 gather ----
#define PCHUNK 32
__global__ __launch_bounds__(512, 1) void gather_kernel(
    const int* __restrict__ hist_tokens, const int* __restrict__ seg,
    const unsigned short* __restrict__ embb, unsigned short* __restrict__ histb)
{
    __shared__ int tokoff[PCHUNK * LL];
    const int b = blockIdx.x, tid = threadIdx.x;
    const int lo = lower_bound_i(seg, NP, b);
    const int hi = lower_bound_i(seg, NP, b + 1);
    const float inv = 1.0f / fmaxf((float)(hi - lo), 1.0f);

    // slots: idx = tid + 512*j over [0, 3750): t = idx/75, dquad = idx%75
    int toff[8], doff[8];
    #pragma unroll
    for (int j = 0; j < 8; ++j) {
        int idx = tid + 512 * j;
        if (idx < 3750) { toff[j] = idx / 75; doff[j] = (idx % 75) * 4; }
        else            { toff[j] = 0;        doff[j] = 0; }
    }
    const bool has8 = (tid < 166);

    float4 acc[8];
    #pragma unroll
    for (int j = 0; j < 8; ++j) acc[j] = make_float4(0.f, 0.f, 0.f, 0.f);

    for (int p0 = lo; p0 < hi; p0 += PCHUNK) {
        const int pc = min(PCHUNK, hi - p0);
        __syncthreads();
        for (int j = tid; j < pc * LL; j += 512)
            tokoff[j] = hist_tokens[p0 * LL + j] * DD;
        __syncthreads();
        for (int pp = 0; pp < pc; ++pp) {
            const int* tr = tokoff + pp * LL;
            #pragma unroll
            for (int j = 0; j < 7; ++j) {
                const ushort4 v = *(const ushort4*)(embb + tr[toff[j]] + doff[j]);
                acc[j].x += bf2f(v.x); acc[j].y += bf2f(v.y);
                acc[j].z += bf2f(v.z); acc[j].w += bf2f(v.w);
            }
            if (has8) {
                const ushort4 v = *(const ushort4*)(embb + tr[toff[7]] + doff[7]);
                acc[7].x += bf2f(v.x); acc[7].y += bf2f(v.y);
                acc[7].z += bf2f(v.z); acc[7].w += bf2f(v.w);
            }
        }
    }

    unsigned short* hb = histb + (size_t)b * TP * DP;
    #pragma unroll
    for (int j = 0; j < 8; ++j) {
        if (j < 7 || has8) {
            ushort4 o;
            o.x = f2bf(acc[j].x * inv); o.y = f2bf(acc[j].y * inv);
            o.z = f2bf(acc[j].z * inv); o.w = f2bf(acc[j].w * inv);
            *(ushort4*)(hb + toff[j] * DP + doff[j]) = o;
        }
    }
    // zero pads: t in {50,51} x d[0,320)  +  t<50 x d[300,320)
    for (int i = tid; i < 640 + 1000; i += 512) {
        int t, d;
        if (i < 640) { t = 50 + i / 320; d = i % 320; }
        else         { int j = i - 640; t = j / 20; d = 300 + j % 20; }
        hb[t * DP + d] = 0;
    }
}

// ---- conv: 4 users/block, sA double-buffered (1 barrier/kt), B direct from
//      fragment-ordered global (L1/L2-resident), 8 waves = (user, n-half) ----
__global__ __launch_bounds__(512, 1) void conv_kernel(
    const unsigned short* __restrict__ histb, const unsigned short* __restrict__ W5f,
    const float* __restrict__ bias_all,
    const float* __restrict__ hist_w, const float* __restrict__ hist_b,
    float* __restrict__ out)
{
    __shared__ __align__(16) unsigned short sA[2][UPB * 52 * 40];  // 2 x 16,640 B
    __shared__ __align__(16) float fpool[UPB * NPADF];             // 5,120 B

    const int b = blockIdx.x, tid = threadIdx.x;
    const int wave = tid >> 6, lane = tid & 63;
    const int col = lane & 15, quad = lane >> 4;
    const int u = wave >> 1, h = wave & 1;

    const unsigned short* hbase = histb + (size_t)(b * UPB) * TP * DP;

    v4f acc[3][10];
    #pragma unroll
    for (int m = 0; m < 3; ++m)
        #pragma unroll
        for (int n = 0; n < 10; ++n)
            acc[m][n] = (v4f){0.f, 0.f, 0.f, 0.f};

    // stage kt=0
    for (int idx = tid; idx < UPB * 52 * 4; idx += 512) {
        int uu = idx / 208, r = idx % 208, row = r >> 2, ch = r & 3;
        *(v8s*)(sA[0] + (uu * 52 + row) * 40 + ch * 8) =
            *(const v8s*)(hbase + (size_t)uu * TP * DP + row * DP + 0 * 32 + ch * 8);
    }

    for (int kt = 0; kt < 10; ++kt) {
        __syncthreads();                       // sA[kt&1] staged; dbuf reads of prev iter done
        if (kt < 9) {
            const int nb = (kt + 1) & 1;
            for (int idx = tid; idx < UPB * 52 * 4; idx += 512) {
                int uu = idx / 208, r = idx % 208, row = r >> 2, ch = r & 3;
                *(v8s*)(sA[nb] + (uu * 52 + row) * 40 + ch * 8) =
                    *(const v8s*)(hbase + (size_t)uu * TP * DP + row * DP + (kt + 1) * 32 + ch * 8);
            }
        }
        const unsigned short* Abuf = sA[kt & 1];
        for (int s = 0; s < 5; ++s) {
            v8s a[3];
            #pragma unroll
            for (int m = 0; m < 3; ++m)
                a[m] = *(const v8s*)(Abuf + (u * 52 + m * 16 + col + s) * 40 + quad * 8);
            v8s bf[10];
            const unsigned short* bbase =
                W5f + ((size_t)((kt * 5 + s) * 20 + h * 10)) * 512 + lane * 8;
            #pragma unroll
            for (int n = 0; n < 10; ++n)
                bf[n] = *(const v8s*)(bbase + n * 512);
            #pragma unroll
            for (int n = 0; n < 10; ++n)
                #pragma unroll
                for (int m = 0; m < 3; ++m)
                    acc[m][n] = __builtin_amdgcn_mfma_f32_16x16x32_bf16(a[m], bf[n], acc[m][n], 0, 0, 0);
        }
    }

    // maxpool + bias + relu -> fpool
    #pragma unroll
    for (int n = 0; n < 10; ++n) {
        const int nf = (h * 10 + n) * 16 + col;
        const int Tout = 48 - nf / 100;        // 48/47/46 (pad filters unused)
        float mx = -1e30f;
        #pragma unroll
        for (int m = 0; m < 3; ++m)
            #pragma unroll
            for (int r = 0; r < 4; ++r) {
                int t = m * 16 + quad * 4 + r;
                if (t < Tout) mx = fmaxf(mx, acc[m][n][r]);
            }
        mx = fmaxf(mx, __shfl_xor(mx, 16, 64));
        mx = fmaxf(mx, __shfl_xor(mx, 32, 64));
        if (quad == 0 && nf < NTOT)
            fpool[u * NPADF + nf] = fmaxf(0.f, mx + bias_all[nf]);
    }
    __syncthreads();

    // rec = fpool @ hist_w.T + hist_b
    if (tid < UPB * 64) {
        const int uu = tid >> 6, o = tid & 63;
        const float4* fw = (const float4*)(hist_w + o * NTOT);
        const float4* fp = (const float4*)(fpool + uu * NPADF);
        float s = 0.f;
        #pragma unroll
        for (int q = 0; q < NTOT / 4; ++q) {
            float4 aa = fp[q], ww = fw[q];
            s += aa.x * ww.x + aa.y * ww.y + aa.z * ww.z + aa.w * ww.w;
        }
        out[(b * UPB + uu) * 64 + o] = s + hist_b[o];
    }
}

// ---- fc via MFMA: h = relu(x[root] @ w1b.T + b1) ; out += h @ w2.T + b2 ----
__global__ __launch_bounds__(256, 1) void fc_mfma(
    const float* __restrict__ x, const int* __restrict__ rootindex,
    const unsigned short* __restrict__ w1b, const float* __restrict__ b1,
    const float* __restrict__ w2, const float* __restrict__ b2,
    float* __restrict__ out)
{
    __shared__ __align__(16) unsigned short sA[FCM * 72];   // 16 rows x 64k (pad 72)
    __shared__ __align__(16) float hl[FCM * 132];           // h tile, stride 132
    __shared__ __align__(16) float w2l[64 * 129];           // w2 staged, stride 129
    __shared__ int roots[FCM];

    const int b = blockIdx.x, tid = threadIdx.x;
    if (tid < FCM) roots[tid] = rootindex[b * FCM + tid];
    for (int i = tid; i < 64 * HID2; i += 256)
        w2l[(i >> 7) * 129 + (i & 127)] = w2[i];
    __syncthreads();

    const int wave = tid >> 6, lane = tid & 63;
    const int col = lane & 15, quad = lane >> 4;

    v4f acc[2];
    acc[0] = (v4f){0.f, 0.f, 0.f, 0.f};
    acc[1] = (v4f){0.f, 0.f, 0.f, 0.f};

    const int r_st = tid >> 4, q_st = tid & 15;

    for (int kt = 0; kt < 12; ++kt) {
        __syncthreads();
        float4 v = *(const float4*)(x + (size_t)roots[r_st] * INFEAT + kt * 64 + q_st * 4);
        ushort4 o; o.x = f2bf(v.x); o.y = f2bf(v.y); o.z = f2bf(v.z); o.w = f2bf(v.w);
        *(ushort4*)(sA + r_st * 72 + q_st * 4) = o;
        __syncthreads();
        #pragma unroll
        for (int kc = 0; kc < 2; ++kc) {
            const v8s a = *(const v8s*)(sA + col * 72 + kc * 32 + quad * 8);
            #pragma unroll
            for (int n = 0; n < 2; ++n) {
                const int nf = (wave * 2 + n) * 16 + col;
                const v8s bfr = *(const v8s*)(w1b + (size_t)nf * INFEAT + kt * 64 + kc * 32 + quad * 8);
                acc[n] = __builtin_amdgcn_mfma_f32_16x16x32_bf16(a, bfr, acc[n], 0, 0, 0);
            }
        }
    }

    #pragma unroll
    for (int nt = 0; nt < 2; ++nt) {
        const int n = (wave * 2 + nt) * 16 + col;
        const float bv = b1[n];
        #pragma unroll
        for (int r = 0; r < 4; ++r)
            hl[(quad * 4 + r) * 132 + n] = fmaxf(acc[nt][r] + bv, 0.f);
    }
    __syncthreads();

    {
        const int o = tid & 63, ug = tid >> 6;
        const float b2v = b2[o];
        const float* wrow = w2l + o * 129;
        #pragma unroll
        for (int i = 0; i < 4; ++i) {
            const int u = ug * 4 + i;
            const float* hrow = hl + u * 132;
            float s = 0.f;
            #pragma unroll 16
            for (int k = 0; k < HID2; ++k) s += hrow[k] * wrow[k];
            out[(b * FCM + u) * 64 + o] += s + b2v;
        }
    }
}

extern "C" void kernel_launch(void* const* d_in, const int* in_sizes, int n_in,
                              void* d_out, int out_size, void* d_ws, size_t ws_size,
                              hipStream_t stream) {
    const float* x        = (const float*)d_in[0];
    const int*   rootidx  = (const int*)d_in[1];
    const int*   hist_tok = (const int*)d_in[2];
    const int*   seg      = (const int*)d_in[3];
    const float* emb      = (const float*)d_in[4];
    const float* w3       = (const float*)d_in[5];
    const float* cb3      = (const float*)d_in[6];
    const float* w4       = (const float*)d_in[7];
    const float* cb4      = (const float*)d_in[8];
    const float* w5       = (const float*)d_in[9];
    const float* cb5      = (const float*)d_in[10];
    const float* hist_w   = (const float*)d_in[11];
    const float* hist_b   = (const float*)d_in[12];
    const float* fw1      = (const float*)d_in[13];
    const float* fb1      = (const float*)d_in[14];
    const float* fw2      = (const float*)d_in[15];
    const float* fb2      = (const float*)d_in[16];
    float* out = (float*)d_out;

    // workspace layout (bytes)
    char* ws = (char*)d_ws;
    unsigned short* emb_bf  = (unsigned short*)(ws);                    // 30,000,000 B
    unsigned short* hist_bf = (unsigned short*)(ws + 30000000);         // 68,157,440 B
    unsigned short* W5f     = (unsigned short*)(ws + 98157440);         //  1,024,000 B
    float*          bias_all= (float*)(ws + 99181440);                  //      1,280 B
    unsigned short* w1b     = (unsigned short*)(ws + 99182720);         //    196,608 B

    emb_cvt<<<(50000 * DD / 4 + 255) / 256, 256, 0, stream>>>(emb, emb_bf, 50000 * DD / 4);
    emb_cvt<<<(HID2 * INFEAT / 4 + 255) / 256, 256, 0, stream>>>(fw1, w1b, HID2 * INFEAT / 4);
    prep_w<<<(10 * 5 * 20 * 512 + 255) / 256, 256, 0, stream>>>(w3, w4, w5, cb3, cb4, cb5, W5f, bias_all);
    gather_kernel<<<NB, 512, 0, stream>>>(hist_tok, seg, emb_bf, hist_bf);
    conv_kernel<<<NB / UPB, 512, 0, stream>>>(hist_bf, W5f, bias_all, hist_w, hist_b, out);
    fc_mfma<<<NB / FCM, 256, 0, stream>>>(x, rootidx, w1b, fb1, fw2, fb2, out);
}

// Round 6
// 352.255 us; speedup vs baseline: 1.5222x; 1.5222x over previous
//
#include <hip/hip_runtime.h>

// Problem constants
#define NB    2048     // users / segments
#define NP    16384    // posts
#define LL    50       // tokens per post
#define DD    300      // embedding dim
#define DP    320      // d padded to multiple of 32 (MFMA K tiles)
#define TP    52       // t rows incl. zero pad (48 outputs + 4 shift overhang)
#define NTOT  300      // total filters (100 per conv)
#define NPADF 320      // filters padded to 20 N-tiles of 16
#define INFEAT 768
#define HID2  128
#define UPB   4        // users per conv block
#define FCM   16       // users per fc block

typedef short v8s __attribute__((ext_vector_type(8)));
typedef float v4f __attribute__((ext_vector_type(4)));

__device__ __forceinline__ unsigned short f2bf(float f) {
    union { float f; unsigned u; } v; v.f = f;
    return (unsigned short)((v.u + 0x7FFF + ((v.u >> 16) & 1)) >> 16);  // RNE
}
__device__ __forceinline__ float bf2f(unsigned short u) {
    union { unsigned u; float f; } v; v.u = ((unsigned)u) << 16; return v.f;
}
__device__ __forceinline__ int lower_bound_i(const int* __restrict__ a, int n, int v) {
    int lo = 0, hi = n;
    while (lo < hi) { int mid = (lo + hi) >> 1; if (a[mid] < v) lo = mid + 1; else hi = mid; }
    return lo;
}

// ---- generic fp32 -> bf16 (used for emb table and fc_w1) ----
__global__ void emb_cvt(const float* __restrict__ in, unsigned short* __restrict__ out, int n4) {
    int i = blockIdx.x * blockDim.x + threadIdx.x;
    if (i >= n4) return;
    float4 v = ((const float4*)in)[i];
    ushort4 o; o.x = f2bf(v.x); o.y = f2bf(v.y); o.z = f2bf(v.z); o.w = f2bf(v.w);
    ((ushort4*)out)[i] = o;
}

// ---- conv weights -> bf16 fragment-order W5f[step=kt*5+s][nt][lane][8] + bias_all ----
__global__ void prep_w(const float* __restrict__ w3, const float* __restrict__ w4,
                       const float* __restrict__ w5,
                       const float* __restrict__ b3, const float* __restrict__ b4,
                       const float* __restrict__ b5,
                       unsigned short* __restrict__ W5f, float* __restrict__ bias_all) {
    int idx = blockIdx.x * blockDim.x + threadIdx.x;
    if (idx < NPADF) {
        float bv = 0.f;
        if (idx < 100) bv = b3[idx];
        else if (idx < 200) bv = b4[idx - 100];
        else if (idx < 300) bv = b5[idx - 200];
        bias_all[idx] = bv;
    }
    if (idx >= 10 * 5 * 20 * 512) return;
    int j    = idx & 7;
    int lane = (idx >> 3) & 63;
    int rest = idx >> 9;            // kt*100 + s*20 + nt
    int nt = rest % 20;
    int s  = (rest / 20) % 5;
    int kt = rest / 100;
    int col = lane & 15, quad = lane >> 4;
    int nf = nt * 16 + col;
    int d  = kt * 32 + quad * 8 + j;
    float v = 0.f;
    if (nf < NTOT && d < DD) {
        int cls = nf / 100, f = nf % 100, K = cls + 3;
        if (s < K) {
            const float* w = (cls == 0) ? w3 : (cls == 1) ? w4 : w5;
            v = w[(f * DD + d) * K + s];
        }
    }
    W5f[idx] = f2bf(v);
}

// ---- ragged segment-mean -> bf16 hist[b][52][320], vectorized ushort4 gather ----
#define PCHUNK 32
__global__ __launch_bounds__(512, 1) void gather_kernel(
    const int* __restrict__ hist_tokens, const int* __restrict__ seg,
    const unsigned short* __restrict__ embb, unsigned short* __restrict__ histb)
{
    __shared__ int tokoff[PCHUNK * LL];
    const int b = blockIdx.x, tid = threadIdx.x;
    const int lo = lower_bound_i(seg, NP, b);
    const int hi = lower_bound_i(seg, NP, b + 1);
    const float inv = 1.0f / fmaxf((float)(hi - lo), 1.0f);

    int toff[8], doff[8];
    #pragma unroll
    for (int j = 0; j < 8; ++j) {
        int idx = tid + 512 * j;
        if (idx < 3750) { toff[j] = idx / 75; doff[j] = (idx % 75) * 4; }
        else            { toff[j] = 0;        doff[j] = 0; }
    }
    const bool has8 = (tid < 166);

    float4 acc[8];
    #pragma unroll
    for (int j = 0; j < 8; ++j) acc[j] = make_float4(0.f, 0.f, 0.f, 0.f);

    for (int p0 = lo; p0 < hi; p0 += PCHUNK) {
        const int pc = min(PCHUNK, hi - p0);
        __syncthreads();
        for (int j = tid; j < pc * LL; j += 512)
            tokoff[j] = hist_tokens[p0 * LL + j] * DD;
        __syncthreads();
        for (int pp = 0; pp < pc; ++pp) {
            const int* tr = tokoff + pp * LL;
            #pragma unroll
            for (int j = 0; j < 7; ++j) {
                const ushort4 v = *(const ushort4*)(embb + tr[toff[j]] + doff[j]);
                acc[j].x += bf2f(v.x); acc[j].y += bf2f(v.y);
                acc[j].z += bf2f(v.z); acc[j].w += bf2f(v.w);
            }
            if (has8) {
                const ushort4 v = *(const ushort4*)(embb + tr[toff[7]] + doff[7]);
                acc[7].x += bf2f(v.x); acc[7].y += bf2f(v.y);
                acc[7].z += bf2f(v.z); acc[7].w += bf2f(v.w);
            }
        }
    }

    unsigned short* hb = histb + (size_t)b * TP * DP;
    #pragma unroll
    for (int j = 0; j < 8; ++j) {
        if (j < 7 || has8) {
            ushort4 o;
            o.x = f2bf(acc[j].x * inv); o.y = f2bf(acc[j].y * inv);
            o.z = f2bf(acc[j].z * inv); o.w = f2bf(acc[j].w * inv);
            *(ushort4*)(hb + toff[j] * DP + doff[j]) = o;
        }
    }
    for (int i = tid; i < 640 + 1000; i += 512) {
        int t, d;
        if (i < 640) { t = 50 + i / 320; d = i % 320; }
        else         { int j = i - 640; t = j / 20; d = 300 + j % 20; }
        hb[t * DP + d] = 0;
    }
}

// ---- conv: 4 users/block, software-pipelined; 1 barrier per (kt,s) step.
//      B (fragment-ordered) dbuf-staged via VGPR prefetch issued before the
//      MFMA batch, written to LDS after it; A dbuf per kt the same way. ----
__global__ __launch_bounds__(512, 1) void conv_kernel(
    const unsigned short* __restrict__ histb, const unsigned short* __restrict__ W5f,
    const float* __restrict__ bias_all,
    const float* __restrict__ hist_w, const float* __restrict__ hist_b,
    float* __restrict__ out)
{
    __shared__ __align__(16) unsigned short sA[2][UPB * 52 * 40];  // 2 x 16,640 B
    __shared__ __align__(16) unsigned short sB[2][20 * 512];       // 2 x 20,480 B
    __shared__ __align__(16) float fpool[UPB * NPADF];             // 5,120 B

    const int b = blockIdx.x, tid = threadIdx.x;
    const int wave = tid >> 6, lane = tid & 63;
    const int col = lane & 15, quad = lane >> 4;
    const int u = wave >> 1, h = wave & 1;

    const unsigned short* hbase = histb + (size_t)(b * UPB) * TP * DP;

    // A-chunk decode for staging (chunk c in [0,832))
    const int c0 = tid, c1 = tid + 512;
    const int a0_uu = c0 / 208, a0_r = c0 % 208;
    const int a0_row = a0_r >> 2, a0_ch = a0_r & 3;
    const int a1_uu = c1 / 208, a1_r = c1 % 208;
    const int a1_row = a1_r >> 2, a1_ch = a1_r & 3;
    const bool hasA1 = (c1 < 832);
    const bool hasB2 = (tid < 256);            // chunk tid+1024 < 1280

    v4f acc[3][10];
    #pragma unroll
    for (int m = 0; m < 3; ++m)
        #pragma unroll
        for (int n = 0; n < 10; ++n)
            acc[m][n] = (v4f){0.f, 0.f, 0.f, 0.f};

    // ---- prologue: stage A(kt=0) into sA[0], B(step=0) into sB[0] ----
    {
        v8s a0 = *(const v8s*)(hbase + (size_t)a0_uu * TP * DP + a0_row * DP + a0_ch * 8);
        v8s a1v;
        if (hasA1) a1v = *(const v8s*)(hbase + (size_t)a1_uu * TP * DP + a1_row * DP + a1_ch * 8);
        v8s t0 = *(const v8s*)(W5f + (size_t)tid * 8);
        v8s t1 = *(const v8s*)(W5f + (size_t)(tid + 512) * 8);
        v8s t2;
        if (hasB2) t2 = *(const v8s*)(W5f + (size_t)(tid + 1024) * 8);
        *(v8s*)(sA[0] + (a0_uu * 52 + a0_row) * 40 + a0_ch * 8) = a0;
        if (hasA1) *(v8s*)(sA[0] + (a1_uu * 52 + a1_row) * 40 + a1_ch * 8) = a1v;
        *(v8s*)(sB[0] + tid * 8) = t0;
        *(v8s*)(sB[0] + (tid + 512) * 8) = t1;
        if (hasB2) *(v8s*)(sB[0] + (tid + 1024) * 8) = t2;
    }

    const int bread_off = (h * 10) * 512 + lane * 8;   // this wave's first B frag in LDS

    for (int kt = 0; kt < 10; ++kt) {
        const unsigned short* Abuf = sA[kt & 1];
        for (int s = 0; s < 5; ++s) {
            const int step = kt * 5 + s;
            __syncthreads();                   // sA[kt&1] + sB[step&1] staged

            // -- prefetch next B step into VGPRs --
            v8s t0, t1, t2;
            const bool haveB = (step < 49);
            if (haveB) {
                const unsigned short* gb = W5f + (size_t)(step + 1) * 10240;
                t0 = *(const v8s*)(gb + tid * 8);
                t1 = *(const v8s*)(gb + (tid + 512) * 8);
                if (hasB2) t2 = *(const v8s*)(gb + (tid + 1024) * 8);
            }
            // -- prefetch next A kt into VGPRs (on last s of each kt) --
            v8s a0v, a1v;
            const bool haveA = (s == 4) && (kt < 9);
            if (haveA) {
                const int ko = (kt + 1) * 32;
                a0v = *(const v8s*)(hbase + (size_t)a0_uu * TP * DP + a0_row * DP + ko + a0_ch * 8);
                if (hasA1)
                    a1v = *(const v8s*)(hbase + (size_t)a1_uu * TP * DP + a1_row * DP + ko + a1_ch * 8);
            }

            // -- compute: 3 A frags + 10 B frags + 30 MFMA --
            const unsigned short* Bbuf = sB[step & 1];
            v8s a[3];
            #pragma unroll
            for (int m = 0; m < 3; ++m)
                a[m] = *(const v8s*)(Abuf + (u * 52 + m * 16 + col + s) * 40 + quad * 8);
            v8s bf[10];
            #pragma unroll
            for (int n = 0; n < 10; ++n)
                bf[n] = *(const v8s*)(Bbuf + bread_off + n * 512);
            #pragma unroll
            for (int n = 0; n < 10; ++n)
                #pragma unroll
                for (int m = 0; m < 3; ++m)
                    acc[m][n] = __builtin_amdgcn_mfma_f32_16x16x32_bf16(a[m], bf[n], acc[m][n], 0, 0, 0);

            // -- writeback prefetches to the other buffers --
            if (haveB) {
                unsigned short* db = sB[(step + 1) & 1];
                *(v8s*)(db + tid * 8) = t0;
                *(v8s*)(db + (tid + 512) * 8) = t1;
                if (hasB2) *(v8s*)(db + (tid + 1024) * 8) = t2;
            }
            if (haveA) {
                unsigned short* da = sA[(kt + 1) & 1];
                *(v8s*)(da + (a0_uu * 52 + a0_row) * 40 + a0_ch * 8) = a0v;
                if (hasA1) *(v8s*)(da + (a1_uu * 52 + a1_row) * 40 + a1_ch * 8) = a1v;
            }
        }
    }

    // maxpool + bias + relu -> fpool
    __syncthreads();
    #pragma unroll
    for (int n = 0; n < 10; ++n) {
        const int nf = (h * 10 + n) * 16 + col;
        const int Tout = 48 - nf / 100;        // 48/47/46 (pad filters unused)
        float mx = -1e30f;
        #pragma unroll
        for (int m = 0; m < 3; ++m)
            #pragma unroll
            for (int r = 0; r < 4; ++r) {
                int t = m * 16 + quad * 4 + r;
                if (t < Tout) mx = fmaxf(mx, acc[m][n][r]);
            }
        mx = fmaxf(mx, __shfl_xor(mx, 16, 64));
        mx = fmaxf(mx, __shfl_xor(mx, 32, 64));
        if (quad == 0 && nf < NTOT)
            fpool[u * NPADF + nf] = fmaxf(0.f, mx + bias_all[nf]);
    }
    __syncthreads();

    // rec = fpool @ hist_w.T + hist_b
    if (tid < UPB * 64) {
        const int uu = tid >> 6, o = tid & 63;
        const float4* fw = (const float4*)(hist_w + o * NTOT);
        const float4* fp = (const float4*)(fpool + uu * NPADF);
        float s = 0.f;
        #pragma unroll
        for (int q = 0; q < NTOT / 4; ++q) {
            float4 aa = fp[q], ww = fw[q];
            s += aa.x * ww.x + aa.y * ww.y + aa.z * ww.z + aa.w * ww.w;
        }
        out[(b * UPB + uu) * 64 + o] = s + hist_b[o];
    }
}

// ---- fc via MFMA: h = relu(x[root] @ w1b.T + b1) ; out += h @ w2.T + b2 ----
__global__ __launch_bounds__(256, 1) void fc_mfma(
    const float* __restrict__ x, const int* __restrict__ rootindex,
    const unsigned short* __restrict__ w1b, const float* __restrict__ b1,
    const float* __restrict__ w2, const float* __restrict__ b2,
    float* __restrict__ out)
{
    __shared__ __align__(16) unsigned short sA[FCM * 72];   // 16 rows x 64k (pad 72)
    __shared__ __align__(16) float hl[FCM * 132];           // h tile, stride 132
    __shared__ __align__(16) float w2l[64 * 129];           // w2 staged, stride 129
    __shared__ int roots[FCM];

    const int b = blockIdx.x, tid = threadIdx.x;
    if (tid < FCM) roots[tid] = rootindex[b * FCM + tid];
    for (int i = tid; i < 64 * HID2; i += 256)
        w2l[(i >> 7) * 129 + (i & 127)] = w2[i];
    __syncthreads();

    const int wave = tid >> 6, lane = tid & 63;
    const int col = lane & 15, quad = lane >> 4;

    v4f acc[2];
    acc[0] = (v4f){0.f, 0.f, 0.f, 0.f};
    acc[1] = (v4f){0.f, 0.f, 0.f, 0.f};

    const int r_st = tid >> 4, q_st = tid & 15;

    for (int kt = 0; kt < 12; ++kt) {
        __syncthreads();
        float4 v = *(const float4*)(x + (size_t)roots[r_st] * INFEAT + kt * 64 + q_st * 4);
        ushort4 o; o.x = f2bf(v.x); o.y = f2bf(v.y); o.z = f2bf(v.z); o.w = f2bf(v.w);
        *(ushort4*)(sA + r_st * 72 + q_st * 4) = o;
        __syncthreads();
        #pragma unroll
        for (int kc = 0; kc < 2; ++kc) {
            const v8s a = *(const v8s*)(sA + col * 72 + kc * 32 + quad * 8);
            #pragma unroll
            for (int n = 0; n < 2; ++n) {
                const int nf = (wave * 2 + n) * 16 + col;
                const v8s bfr = *(const v8s*)(w1b + (size_t)nf * INFEAT + kt * 64 + kc * 32 + quad * 8);
                acc[n] = __builtin_amdgcn_mfma_f32_16x16x32_bf16(a, bfr, acc[n], 0, 0, 0);
            }
        }
    }

    #pragma unroll
    for (int nt = 0; nt < 2; ++nt) {
        const int n = (wave * 2 + nt) * 16 + col;
        const float bv = b1[n];
        #pragma unroll
        for (int r = 0; r < 4; ++r)
            hl[(quad * 4 + r) * 132 + n] = fmaxf(acc[nt][r] + bv, 0.f);
    }
    __syncthreads();

    {
        const int o = tid & 63, ug = tid >> 6;
        const float b2v = b2[o];
        const float* wrow = w2l + o * 129;
        #pragma unroll
        for (int i = 0; i < 4; ++i) {
            const int u = ug * 4 + i;
            const float* hrow = hl + u * 132;
            float s = 0.f;
            #pragma unroll 16
            for (int k = 0; k < HID2; ++k) s += hrow[k] * wrow[k];
            out[(b * FCM + u) * 64 + o] += s + b2v;
        }
    }
}

extern "C" void kernel_launch(void* const* d_in, const int* in_sizes, int n_in,
                              void* d_out, int out_size, void* d_ws, size_t ws_size,
                              hipStream_t stream) {
    const float* x        = (const float*)d_in[0];
    const int*   rootidx  = (const int*)d_in[1];
    const int*   hist_tok = (const int*)d_in[2];
    const int*   seg      = (const int*)d_in[3];
    const float* emb      = (const float*)d_in[4];
    const float* w3       = (const float*)d_in[5];
    const float* cb3      = (const float*)d_in[6];
    const float* w4       = (const float*)d_in[7];
    const float* cb4      = (const float*)d_in[8];
    const float* w5       = (const float*)d_in[9];
    const float* cb5      = (const float*)d_in[10];
    const float* hist_w   = (const float*)d_in[11];
    const float* hist_b   = (const float*)d_in[12];
    const float* fw1      = (const float*)d_in[13];
    const float* fb1      = (const float*)d_in[14];
    const float* fw2      = (const float*)d_in[15];
    const float* fb2      = (const float*)d_in[16];
    float* out = (float*)d_out;

    // workspace layout (bytes)
    char* ws = (char*)d_ws;
    unsigned short* emb_bf  = (unsigned short*)(ws);                    // 30,000,000 B
    unsigned short* hist_bf = (unsigned short*)(ws + 30000000);         // 68,157,440 B
    unsigned short* W5f     = (unsigned short*)(ws + 98157440);         //  1,024,000 B
    float*          bias_all= (float*)(ws + 99181440);                  //      1,280 B
    unsigned short* w1b     = (unsigned short*)(ws + 99182720);         //    196,608 B

    emb_cvt<<<(50000 * DD / 4 + 255) / 256, 256, 0, stream>>>(emb, emb_bf, 50000 * DD / 4);
    emb_cvt<<<(HID2 * INFEAT / 4 + 255) / 256, 256, 0, stream>>>(fw1, w1b, HID2 * INFEAT / 4);
    prep_w<<<(10 * 5 * 20 * 512 + 255) / 256, 256, 0, stream>>>(w3, w4, w5, cb3, cb4, cb5, W5f, bias_all);
    gather_kernel<<<NB, 512, 0, stream>>>(hist_tok, seg, emb_bf, hist_bf);
    conv_kernel<<<NB / UPB, 512, 0, stream>>>(hist_bf, W5f, bias_all, hist_w, hist_b, out);
    fc_mfma<<<NB / FCM, 256, 0, stream>>>(x, rootidx, w1b, fb1, fw2, fb2, out);
}